// Round 9
// baseline (117.892 us; speedup 1.0000x reference)
//
#include <hip/hip_runtime.h>
#include <hip/hip_bf16.h>

// Problem constants (fixed by reference setup_inputs)
#define I_DIM  7168
#define O_DIM  18432
#define SW     56      // I_DIM/128 (scale row stride)
#define BN     32      // O rows per block (single 32x32 MFMA tile)
#define ROWS   64      // 32 W rows + 32 x rows staged per tile
#define BK     64      // K floats per tile (never straddles a 128-scale block)
#define NTILES 112     // I_DIM/BK — full K per block: KC=1, no atomics/memset
#define NBLK   576     // O_DIM/BN

typedef float  f32x4  __attribute__((ext_vector_type(4)));
typedef float  f32x16 __attribute__((ext_vector_type(16)));
typedef __bf16 bf16x8 __attribute__((ext_vector_type(8)));
typedef __bf16 bf16x4 __attribute__((ext_vector_type(4)));

// Single-wave blocks: wave-private LDS, NO barriers, compiler-managed waitcnts.
// Each block owns a contiguous 896 KB W footprint (32 rows x full K):
// 36K device-wide row-streams vs R8's ~123K -> DRAM page locality probe.
__global__ __launch_bounds__(64, 2) void fp8lin_gemm(
    const float* __restrict__ x,      // [32, 7168]
    const float* __restrict__ w,      // [18432, 7168]
    const float* __restrict__ s,      // [144, 56]
    float* __restrict__ out) {        // [32, 18432]
  __shared__ __bf16 lds[2][ROWS * BK];   // 2 x 8 KiB

  const int tid = threadIdx.x;       // one wave: tid == lane
  const int r   = tid & 31;          // MFMA row/col index
  const int g   = tid >> 5;          // k-group

  const int bid = blockIdx.x;
  const int o0  = bid * BN;

  // Staging coords: round j covers rows j*4 + (tid>>4); col (tid&15)*4 floats.
  // Wave instr = 4 rows x 256 B (16 fully-used lines).
  const int srow = tid >> 4;          // 0..3
  const int scol = (tid & 15) * 4;    // float col within BK

  // Double-buffered staging registers: issue(t+1) has no WAR on writeb(t).
  f32x4 LA[16], LB[16];

  auto issue = [&](f32x4 (&L)[16], int t) {
    const int kk = t * BK;
#pragma unroll
    for (int j = 0; j < 16; ++j) {
      const int row = j * 4 + srow;   // 0..63
      if (j < 8) {
        // W read exactly once -> nontemporal (R8: +10%, don't churn L2/L3)
        const float* p = w + (size_t)(o0 + row) * I_DIM + kk + scol;
        L[j] = __builtin_nontemporal_load(reinterpret_cast<const f32x4*>(p));
      } else {
        // x is hot (L2-resident, re-read by every block): keep cached.
        const float* p = x + (size_t)(row - 32) * I_DIM + kk + scol;
        L[j] = *reinterpret_cast<const f32x4*>(p);
      }
    }
  };

  auto writeb = [&](const f32x4 (&L)[16], int buf, float sc) {
    char* base = (char*)&lds[buf][0];
#pragma unroll
    for (int j = 0; j < 16; ++j) {
      const int row = j * 4 + srow;
      const float scale = (j < 8) ? sc : 1.0f;   // x rows unscaled
      bf16x4 v;
      v[0] = (__bf16)(L[j][0] * scale);
      v[1] = (__bf16)(L[j][1] * scale);
      v[2] = (__bf16)(L[j][2] * scale);
      v[3] = (__bf16)(L[j][3] * scale);
      int byte = row * (BK * 2) + scol * 2;      // [row][col] bf16, 128 B rows
      byte ^= ((row & 7) << 4);                  // T2 swizzle (write side)
      *reinterpret_cast<bf16x4*>(base + byte) = v;
    }
  };

  f32x16 acc;
#pragma unroll
  for (int i = 0; i < 16; ++i) acc[i] = 0.0f;

  const int xrow = 32 + r;           // x staged at tile rows 32..63
  const int wrow = r;                // W staged at tile rows 0..31
  const int xswz = (xrow & 7) << 4;
  const int wswz = (wrow & 7) << 4;

  auto compute = [&](int buf) {
    const char* base = (const char*)&lds[buf][0];
#pragma unroll
    for (int kb = 0; kb < BK; kb += 16) {
      const int cb = kb * 2 + g * 16;
      bf16x8 a = *reinterpret_cast<const bf16x8*>(base + ((xrow * 128 + cb) ^ xswz));
      bf16x8 b = *reinterpret_cast<const bf16x8*>(base + ((wrow * 128 + cb) ^ wswz));
      acc = __builtin_amdgcn_mfma_f32_32x32x16_bf16(a, b, acc, 0, 0, 0);
    }
  };

  const float* srow_p = s + (o0 >> 7) * SW;   // this block's scale row

  issue(LA, 0);
  for (int t = 0; t < NTILES; t += 2) {
    // even tile t -> buf 0, staged in LA
    issue(LB, t + 1);                         // t+1 <= 111 always
    writeb(LA, 0, srow_p[(t * BK) >> 7]);
    compute(0);                               // compiler inserts lgkmcnt

    // odd tile t+1 -> buf 1, staged in LB
    if (t + 2 < NTILES) issue(LA, t + 2);
    writeb(LB, 1, srow_p[((t + 1) * BK) >> 7]);
    compute(1);
  }

  // C/D layout (32x32, verified m74/m101): col=lane&31, row=(reg&3)+8*(reg>>2)+4*g
  // KC=1 -> plain stores; every out element written exactly once.
  float* op = out + o0 + r;
#pragma unroll
  for (int reg = 0; reg < 16; ++reg) {
    const int row = (reg & 3) + 8 * (reg >> 2) + 4 * g;
    op[(size_t)row * O_DIM] = acc[reg];
  }
}

extern "C" void kernel_launch(void* const* d_in, const int* in_sizes, int n_in,
                              void* d_out, int out_size, void* d_ws, size_t ws_size,
                              hipStream_t stream) {
  const float* x = (const float*)d_in[0];
  const float* w = (const float*)d_in[1];
  const float* s = (const float*)d_in[2];
  float* out = (float*)d_out;

  dim3 grid(NBLK);   // 576 single-wave blocks, all co-resident (2-3 per CU)
  dim3 block(64);
  fp8lin_gemm<<<grid, block, 0, stream>>>(x, w, s, out);
}